// Round 1
// baseline (503.779 us; speedup 1.0000x reference)
//
#include <hip/hip_runtime.h>
#include <math.h>

#define NE 256
#define EDIM 1024
#define HW 1024
#define NB 16
#define NPIX 16384              // NB * HW
#define OUT_ELEMS 16777216      // NB * EDIM * HW

// workspace layout (bytes)
#define WS_CE2   0              // float[256]
#define WS_HIST  1024           // int[256]
#define WS_LOSS  2048           // float[1]
#define WS_IDX   4096           // int[16384]
#define WS_T     69632          // float[1024*256]
#define WS_TOTAL (69632 + 1048576)

// ---------------- codebook half-squared-norms: ce2[j] = 0.5*||emb_j||^2 ----
__global__ __launch_bounds__(64) void k_norms(const float* __restrict__ emb,
                                              float* __restrict__ ce2) {
    int j = blockIdx.x;
    int lane = threadIdx.x;
    const float* row = emb + (size_t)j * EDIM;
    float s = 0.f;
    #pragma unroll
    for (int i = 0; i < EDIM / 64; i++) {
        float v = row[lane + 64 * i];
        s += v * v;
    }
    #pragma unroll
    for (int m = 32; m; m >>= 1) s += __shfl_down(s, m, 64);
    if (lane == 0) ce2[j] = 0.5f * s;
}

// ---------------- T[o][j] = sum_c w[o][c] * emb[j][c]  (split-K, atomics) ---
// grid (4 jtiles, 16 otiles, 4 ksplits), 256 threads, 64x64 tile, Kslice=256
__global__ __launch_bounds__(256) void k_wT(const float* __restrict__ w,
                                            const float* __restrict__ emb,
                                            float* __restrict__ T) {
    __shared__ float wt[64 * 17];
    __shared__ float et[64 * 17];
    int t = threadIdx.x;
    int j0 = blockIdx.x * 64;
    int o0 = blockIdx.y * 64;
    int kb = blockIdx.z * 256;
    int to = t & 15, tj = t >> 4;
    float acc[4][4] = {};
    int lr = t >> 2, lk = (t & 3) * 4;
    for (int kk = kb; kk < kb + 256; kk += 16) {
        float4 wv = *(const float4*)(w + (size_t)(o0 + lr) * EDIM + kk + lk);
        float4 ev = *(const float4*)(emb + (size_t)(j0 + lr) * EDIM + kk + lk);
        __syncthreads();   // previous iteration's LDS reads done
        wt[lr * 17 + lk + 0] = wv.x; wt[lr * 17 + lk + 1] = wv.y;
        wt[lr * 17 + lk + 2] = wv.z; wt[lr * 17 + lk + 3] = wv.w;
        et[lr * 17 + lk + 0] = ev.x; et[lr * 17 + lk + 1] = ev.y;
        et[lr * 17 + lk + 2] = ev.z; et[lr * 17 + lk + 3] = ev.w;
        __syncthreads();
        #pragma unroll
        for (int k = 0; k < 16; k++) {
            float a[4], b[4];
            #pragma unroll
            for (int i = 0; i < 4; i++) a[i] = wt[(to * 4 + i) * 17 + k];
            #pragma unroll
            for (int i = 0; i < 4; i++) b[i] = et[(tj * 4 + i) * 17 + k];
            #pragma unroll
            for (int i = 0; i < 4; i++)
                #pragma unroll
                for (int jx = 0; jx < 4; jx++) acc[i][jx] += a[i] * b[jx];
        }
    }
    #pragma unroll
    for (int i = 0; i < 4; i++)
        #pragma unroll
        for (int jx = 0; jx < 4; jx++)
            atomicAdd(&T[(size_t)(o0 + to * 4 + i) * NE + j0 + tj * 4 + jx],
                      acc[i][jx]);
}

// ---------------- distance + argmin + loss partials + histogram ------------
// grid 256 blocks (64 pixels each), 256 threads; each thread: 8 px x 8 codes
__global__ __launch_bounds__(256) void k_argmin(const float* __restrict__ z,
                                                const float* __restrict__ emb,
                                                const float* __restrict__ ce2,
                                                int* __restrict__ idx_i,
                                                float* __restrict__ idx_f,
                                                int* __restrict__ hist,
                                                float* __restrict__ loss_acc) {
    __shared__ float zt[32 * 64];      // [k][p]
    __shared__ float et[256 * 34];     // [code][k], pad 34
    __shared__ float znorm_s[64];
    int t = threadIdx.x;
    int n0 = blockIdx.x * 64;          // global pixel base (never crosses batch)
    int b = n0 >> 10;
    int p0 = n0 & 1023;
    const float* zb = z + (size_t)b * EDIM * HW;   // [c][p] for this batch
    int tc = t & 31, tp = t >> 5;

    float acc[8][8] = {};
    float znorm = 0.f;                 // thread t<64 owns local pixel t

    for (int kk = 0; kk < EDIM; kk += 32) {
        // stage E tile: 256 codes x 32 k, as float2 along k
        #pragma unroll
        for (int i = 0; i < 16; i++) {
            int q = t + 256 * i;       // 0..4095
            int code = q >> 4, k2 = q & 15;
            float2 v = *(const float2*)(emb + (size_t)code * EDIM + kk + k2 * 2);
            *(float2*)(et + code * 34 + k2 * 2) = v;
        }
        // stage Z tile: 32 k x 64 p, k-major
        #pragma unroll
        for (int i = 0; i < 4; i++) {
            int q = t + 256 * i;       // 0..1023
            int k = q >> 5, p2 = q & 31;
            float2 v = *(const float2*)(zb + (size_t)(kk + k) * HW + p0 + p2 * 2);
            *(float2*)(zt + k * 64 + p2 * 2) = v;
        }
        __syncthreads();
        if (t < 64) {
            #pragma unroll
            for (int k = 0; k < 32; k++) { float zz = zt[k * 64 + t]; znorm += zz * zz; }
        }
        #pragma unroll 4
        for (int k2 = 0; k2 < 16; k2++) {
            float2 ev[8], za[4], zb2[4];
            #pragma unroll
            for (int u = 0; u < 8; u++)
                ev[u] = *(float2*)(et + (tc + 32 * u) * 34 + k2 * 2);
            #pragma unroll
            for (int j = 0; j < 4; j++)
                za[j] = *(float2*)(zt + (2 * k2) * 64 + tp * 8 + 2 * j);
            #pragma unroll
            for (int j = 0; j < 4; j++)
                zb2[j] = *(float2*)(zt + (2 * k2 + 1) * 64 + tp * 8 + 2 * j);
            #pragma unroll
            for (int p = 0; p < 8; p++) {
                float z0 = (p & 1) ? za[p >> 1].y : za[p >> 1].x;
                float z1 = (p & 1) ? zb2[p >> 1].y : zb2[p >> 1].x;
                #pragma unroll
                for (int u = 0; u < 8; u++)
                    acc[p][u] += z0 * ev[u].x + z1 * ev[u].y;
            }
        }
        __syncthreads();
    }
    if (t < 64) znorm_s[t] = znorm;

    // per-thread argmin over its 8 codes for each of its 8 pixels
    float minv[8];
    int mini[8];
    #pragma unroll
    for (int p = 0; p < 8; p++) { minv[p] = 3.4e38f; mini[p] = 0; }
    #pragma unroll
    for (int u = 0; u < 8; u++) {
        int code = tc + 32 * u;
        float c2 = ce2[code];
        #pragma unroll
        for (int p = 0; p < 8; p++) {
            float s = c2 - acc[p][u];   // 0.5||e||^2 - z.e
            if (s < minv[p] || (s == minv[p] && code < mini[p])) {
                minv[p] = s; mini[p] = code;
            }
        }
    }
    // reduce across the 32 tc-lanes (lanes stay within their 32-half on xor<32)
    #pragma unroll
    for (int m = 1; m < 32; m <<= 1) {
        #pragma unroll
        for (int p = 0; p < 8; p++) {
            float ov = __shfl_xor(minv[p], m, 64);
            int oi = __shfl_xor(mini[p], m, 64);
            if (ov < minv[p] || (ov == minv[p] && oi < mini[p])) {
                minv[p] = ov; mini[p] = oi;
            }
        }
    }
    __syncthreads();   // znorm_s visible
    if (tc == 0) {
        float dsum = 0.f;
        #pragma unroll
        for (int p = 0; p < 8; p++) {
            int lp = tp * 8 + p;
            int n = n0 + lp;
            idx_i[n] = mini[p];
            idx_f[n] = (float)mini[p];
            dsum += znorm_s[lp] + 2.f * minv[p];   // ||z||^2 + ||e||^2 - 2 z.e
            atomicAdd(&hist[mini[p]], 1);
        }
        atomicAdd(loss_acc, dsum);
    }
}

// ---------------- out[b][o][p] = T[o][idx[b][p]] + bias[o] -----------------
// grid (256 o-groups of 4, 16 batches), 256 threads (1 float4 of p each)
__global__ __launch_bounds__(256) void k_scatter(const float* __restrict__ T,
                                                 const float* __restrict__ bias,
                                                 const int* __restrict__ idx,
                                                 float* __restrict__ out) {
    int t = threadIdx.x;
    int og = blockIdx.x;
    int b = blockIdx.y;
    int4 i4 = *(const int4*)(idx + b * HW + t * 4);
    #pragma unroll
    for (int j = 0; j < 4; j++) {
        int o = og * 4 + j;
        const float* Tr = T + (size_t)o * NE;
        float bb = bias[o];
        float4 r;
        r.x = Tr[i4.x] + bb;
        r.y = Tr[i4.y] + bb;
        r.z = Tr[i4.z] + bb;
        r.w = Tr[i4.w] + bb;
        *(float4*)(out + ((size_t)(b * EDIM + o) * HW) + t * 4) = r;
    }
}

// ---------------- loss + perplexity finalize -------------------------------
__global__ __launch_bounds__(256) void k_final(const int* __restrict__ hist,
                                               const float* __restrict__ loss_acc,
                                               float* __restrict__ out) {
    __shared__ float red[4];
    int t = threadIdx.x;
    float em = (float)hist[t] * (1.0f / 16384.0f);
    float v = em * logf(em + 1e-10f);
    #pragma unroll
    for (int m = 32; m; m >>= 1) v += __shfl_down(v, m, 64);
    if ((t & 63) == 0) red[t >> 6] = v;
    __syncthreads();
    if (t == 0) {
        float s = red[0] + red[1] + red[2] + red[3];
        out[OUT_ELEMS] = loss_acc[0] * 1.25f / 16777216.f;   // (1+beta)*mean
        out[OUT_ELEMS + 1] = expf(-s);
    }
}

extern "C" void kernel_launch(void* const* d_in, const int* in_sizes, int n_in,
                              void* d_out, int out_size, void* d_ws, size_t ws_size,
                              hipStream_t stream) {
    (void)in_sizes; (void)n_in; (void)out_size; (void)ws_size;
    const float* z      = (const float*)d_in[0];
    const float* emb    = (const float*)d_in[1];
    const float* conv_w = (const float*)d_in[2];
    const float* conv_b = (const float*)d_in[3];
    float* out = (float*)d_out;

    float* ce2      = (float*)((char*)d_ws + WS_CE2);
    int*   hist     = (int*)((char*)d_ws + WS_HIST);
    float* loss_acc = (float*)((char*)d_ws + WS_LOSS);
    int*   idx_i    = (int*)((char*)d_ws + WS_IDX);
    float* T        = (float*)((char*)d_ws + WS_T);

    hipMemsetAsync(d_ws, 0, WS_TOTAL, stream);
    k_norms<<<NE, 64, 0, stream>>>(emb, ce2);
    k_wT<<<dim3(4, 16, 4), 256, 0, stream>>>(conv_w, emb, T);
    k_argmin<<<256, 256, 0, stream>>>(z, emb, ce2, idx_i, out + OUT_ELEMS + 2,
                                      hist, loss_acc);
    k_scatter<<<dim3(256, 16), 256, 0, stream>>>(T, conv_b, idx_i, out);
    k_final<<<1, 256, 0, stream>>>(hist, loss_acc, out);
}